// Round 2
// baseline (525.173 us; speedup 1.0000x reference)
//
#include <hip/hip_runtime.h>

// Problem constants (ScaledDotProductAttention: B=16, S=2048, D=64, T=8)
constexpr int NB = 16;
constexpr int NS = 2048;
constexpr int ND = 64;
constexpr int MTILE = 32;              // query rows per block

typedef __attribute__((ext_vector_type(8))) short bh8;     // 8 x bf16 bits (4 VGPRs)
typedef __attribute__((ext_vector_type(4))) float f32x4;   // MFMA accumulator

constexpr int EB_STRIDE = 2048 + 8;    // bf16 elems per ebuf row; 4112B = 257*16 (keeps 16B align, breaks bank pow2)
constexpr int VT_STRIDE = 128 + 8;     // bf16 elems per vbufT row; 272B = 17*16

__device__ __forceinline__ unsigned short f2bf(float x) {
  unsigned u = __float_as_uint(x);
  u += 0x7fffu + ((u >> 16) & 1u);     // round-to-nearest-even
  return (unsigned short)(u >> 16);
}
__device__ __forceinline__ float bf2f(unsigned u16) {
  return __uint_as_float(u16 << 16);
}

__global__ __launch_bounds__(512, 1)
void sdpa_fused_kernel(const float* __restrict__ q, const float* __restrict__ k,
                       const float* __restrict__ v, const int* __restrict__ mask,
                       float* __restrict__ outO, float* __restrict__ outA)
{
  extern __shared__ char smem[];
  unsigned short* ebuf  = (unsigned short*)smem;            // [MTILE][EB_STRIDE] bf16 e=exp(s)
  unsigned short* vbufT = ebuf + MTILE * EB_STRIDE;         // [64][VT_STRIDE]    bf16 V^T tile
  float* rowsumP = (float*)(vbufT + 64 * VT_STRIDE);        // [32][4] partial row sums
  float* invl    = rowsumP + 32 * 4;                        // [32]

  const int tid  = threadIdx.x;
  const int wave = tid >> 6;
  const int lane = tid & 63;
  const int n16  = lane & 15;
  const int quad = lane >> 4;
  const int b     = blockIdx.y;
  const int mbase = blockIdx.x * MTILE;

  // Phase-1 work split: wave -> (row half, 512-col key chunk)
  const int mrow0 = (wave & 1) * 16;
  const int col0  = (wave >> 1) * 512;

  // ---- Q fragments (MFMA A-operand: lane holds A[m=lane&15][k=quad*8+j]), pre-scaled by 1/8
  bh8 aq[2];
  {
    const float* qp = q + ((long)(b * NS + mbase + mrow0 + n16)) * ND + quad * 8;
    #pragma unroll
    for (int kk = 0; kk < 2; ++kk) {
      float4 x0 = *(const float4*)(qp + kk * 32);
      float4 x1 = *(const float4*)(qp + kk * 32 + 4);
      bh8 f;
      f[0] = f2bf(x0.x * 0.125f); f[1] = f2bf(x0.y * 0.125f);
      f[2] = f2bf(x0.z * 0.125f); f[3] = f2bf(x0.w * 0.125f);
      f[4] = f2bf(x1.x * 0.125f); f[5] = f2bf(x1.y * 0.125f);
      f[6] = f2bf(x1.z * 0.125f); f[7] = f2bf(x1.w * 0.125f);
      aq[kk] = f;
    }
  }

  // ---- Phase 1: S = (Q/8)K^T via MFMA, e = mask ? exp(s) : 0 -> ebuf; per-row sums
  float rsum[4] = {0.f, 0.f, 0.f, 0.f};
  for (int nt = 0; nt < 32; ++nt) {
    const int key = col0 + nt * 16 + n16;   // B-operand: lane holds B[k=quad*8+j][n=lane&15] = K[key][kdim]
    const float* kp = k + ((long)(b * NS + key)) * ND + quad * 8;
    f32x4 acc = {0.f, 0.f, 0.f, 0.f};
    #pragma unroll
    for (int kk = 0; kk < 2; ++kk) {
      float4 x0 = *(const float4*)(kp + kk * 32);
      float4 x1 = *(const float4*)(kp + kk * 32 + 4);
      bh8 f;
      f[0] = f2bf(x0.x); f[1] = f2bf(x0.y); f[2] = f2bf(x0.z); f[3] = f2bf(x0.w);
      f[4] = f2bf(x1.x); f[5] = f2bf(x1.y); f[6] = f2bf(x1.z); f[7] = f2bf(x1.w);
      acc = __builtin_amdgcn_mfma_f32_16x16x32_bf16(aq[kk], f, acc, 0, 0, 0);
    }
    // C/D layout: col = lane&15 (== key), row = quad*4 + r
    #pragma unroll
    for (int r = 0; r < 4; ++r) {
      const int lrow = mrow0 + quad * 4 + r;
      const int grow = mbase + lrow;
      const int m = mask[(long)grow * NS + key];
      const float e = m ? __expf(acc[r]) : 0.f;
      rsum[r] += e;
      ebuf[lrow * EB_STRIDE + key] = f2bf(e);
    }
  }

  // reduce row sums across the 16 lanes of each quad-group, stash per-chunk partials
  #pragma unroll
  for (int r = 0; r < 4; ++r) {
    float s = rsum[r];
    s += __shfl_xor(s, 1);
    s += __shfl_xor(s, 2);
    s += __shfl_xor(s, 4);
    s += __shfl_xor(s, 8);
    if (n16 == 0) rowsumP[(mrow0 + quad * 4 + r) * 4 + (wave >> 1)] = s;
  }
  __syncthreads();
  if (tid < 32) {
    const float l = rowsumP[tid * 4 + 0] + rowsumP[tid * 4 + 1] +
                    rowsumP[tid * 4 + 2] + rowsumP[tid * 4 + 3];
    invl[tid] = 1.f / l;
  }
  __syncthreads();

  // ---- Phase 2: attn = e * invl -> global (fp32, float4-coalesced; one row per iteration)
  {
    float* aout = outA + ((long)(b * NS + mbase)) * NS;
    for (int it = 0; it < 32; ++it) {
      const float il = invl[it];
      const unsigned short* ep = ebuf + it * EB_STRIDE + tid * 4;
      uint2 raw = *(const uint2*)ep;
      float4 o;
      o.x = bf2f(raw.x & 0xffffu) * il;
      o.y = bf2f(raw.x >> 16)     * il;
      o.z = bf2f(raw.y & 0xffffu) * il;
      o.w = bf2f(raw.y >> 16)     * il;
      *(float4*)(aout + (long)it * NS + tid * 4) = o;
    }
  }

  // ---- Phase 3: O = P V via MFMA (A = e from ebuf rows, B = V^T staged in LDS), scale by invl at end
  const int mtile = wave & 1;     // 16-row tile of O
  const int dtile = wave >> 1;    // 16-col tile of O
  const int jmy = tid & 127;
  const int g   = tid >> 7;
  f32x4 oacc = {0.f, 0.f, 0.f, 0.f};
  for (int jc = 0; jc < NS; jc += 128) {
    __syncthreads();              // previous chunk's vbufT readers done
    const float4* vsrc = (const float4*)(v + ((long)(b * NS + jc)) * ND);
    #pragma unroll
    for (int i = 0; i < 4; ++i) {
      const int dcol4 = g + 4 * i;                 // which float4 within the V row
      float4 vv = vsrc[(long)jmy * 16 + dcol4];
      const int d0 = dcol4 * 4;
      vbufT[(d0 + 0) * VT_STRIDE + jmy] = f2bf(vv.x);
      vbufT[(d0 + 1) * VT_STRIDE + jmy] = f2bf(vv.y);
      vbufT[(d0 + 2) * VT_STRIDE + jmy] = f2bf(vv.z);
      vbufT[(d0 + 3) * VT_STRIDE + jmy] = f2bf(vv.w);
    }
    __syncthreads();
    #pragma unroll
    for (int kt = 0; kt < 4; ++kt) {   // FIX: 4 x K=32 = all 128 staged keys (was kt<2 -> half the keys)
      bh8 af = *(const bh8*)(ebuf  + (mtile * 16 + n16) * EB_STRIDE + jc + kt * 32 + quad * 8);
      bh8 bf = *(const bh8*)(vbufT + (dtile * 16 + n16) * VT_STRIDE + kt * 32 + quad * 8);
      oacc = __builtin_amdgcn_mfma_f32_16x16x32_bf16(af, bf, oacc, 0, 0, 0);
    }
  }
  #pragma unroll
  for (int r = 0; r < 4; ++r) {
    const int lrow = mtile * 16 + quad * 4 + r;
    outO[((long)(b * NS + mbase + lrow)) * ND + dtile * 16 + n16] = oacc[r] * invl[lrow];
  }
}

extern "C" void kernel_launch(void* const* d_in, const int* in_sizes, int n_in,
                              void* d_out, int out_size, void* d_ws, size_t ws_size,
                              hipStream_t stream) {
  const float* q    = (const float*)d_in[0];
  const float* k    = (const float*)d_in[1];
  const float* v    = (const float*)d_in[2];
  const int*   mask = (const int*)d_in[3];
  float* outO = (float*)d_out;                      // [16,2048,64]
  float* outA = outO + (long)NB * NS * ND;          // [16,2048,2048]

  const size_t lds = (size_t)(MTILE * EB_STRIDE + 64 * VT_STRIDE) * sizeof(short)
                   + (size_t)(32 * 4 + 32) * sizeof(float);
  hipFuncSetAttribute((const void*)sdpa_fused_kernel,
                      hipFuncAttributeMaxDynamicSharedMemorySize, (int)lds);
  dim3 grid(NS / MTILE, NB);
  sdpa_fused_kernel<<<grid, 512, lds, stream>>>(q, k, v, mask, outO, outA);
}